// Round 1
// baseline (180.739 us; speedup 1.0000x reference)
//
#include <hip/hip_runtime.h>
#include <hip/hip_bf16.h>

// MHSA: hidden[2,2048,1024], mask[2,2048] i32, W_qkv[16,1024,192] -> out[2,2048,1024]
// f32-or-bf16 inputs (per-block runtime detection in k_cvt_x). Pipeline:
// cvt X->bf16 (into d_out, dead until attn epilogue), QKV GEMM (global_load_lds
// + XOR-swizzled LDS), flash attention (S^T = K*Q^T, base-2 softmax,
// TRIPLE-buffered async K/V staging with raw s_barrier + manual vmcnt(2)).
// P stays in REGISTERS: S^T's 16x16 C-layout (row=quad*4+reg, col=l15) is
// exactly the B-fragment layout of v_mfma_f32_16x16x16_bf16 (k=quad*4+e,
// col=l15), so PV = 4x K=16 MFMAs consuming the packed exp2 dwords directly
// -- no P LDS round trip, no P bank conflicts, -18KB LDS.

#define NH   16
#define HD   64
#define SEQ  2048
#define HID  1024
#define E3   192
#define QSCALE 0.04508422017f     // (1/32) * log2(e)
#define MBIAS  -43.2808512f       // -30 * log2(e)

typedef __attribute__((ext_vector_type(8))) short short8;
typedef __attribute__((ext_vector_type(4))) short short4v;
typedef __attribute__((ext_vector_type(4))) float f32x4;
typedef unsigned short ushort_t;

#define MFMA16(a, b, c) __builtin_amdgcn_mfma_f32_16x16x32_bf16((a), (b), (c), 0, 0, 0)

// K=16 bf16 MFMA (A/B = 4 bf16 = 2 VGPRs each). Builtin name differs across
// ROCm versions; fall back to inline asm (instruction exists on gfx950).
#if __has_builtin(__builtin_amdgcn_mfma_f32_16x16x16_bf16)
#define MFMA16K16(a, b, c) __builtin_amdgcn_mfma_f32_16x16x16_bf16((a), (b), (c), 0, 0, 0)
#elif __has_builtin(__builtin_amdgcn_mfma_f32_16x16x16bf16_1k)
#define MFMA16K16(a, b, c) __builtin_amdgcn_mfma_f32_16x16x16bf16_1k((a), (b), (c), 0, 0, 0)
#else
static __device__ __forceinline__ f32x4 mfma16k16_asm(short4v a, short4v b, f32x4 c) {
    asm("v_mfma_f32_16x16x16_bf16 %0, %1, %2, %0" : "+v"(c) : "v"(a), "v"(b));
    return c;
}
#define MFMA16K16(a, b, c) mfma16k16_asm((a), (b), (c))
#endif

#if __has_builtin(__builtin_amdgcn_exp2f)
#define EXP2(x) __builtin_amdgcn_exp2f(x)
#else
#define EXP2(x) exp2f(x)
#endif

static __device__ __forceinline__ ushort_t f2bf(float x) {
    unsigned u = __builtin_bit_cast(unsigned, x);
    unsigned r = u + 0x7fff + ((u >> 16) & 1);   // RNE
    return (ushort_t)(r >> 16);
}

static __device__ __forceinline__ unsigned pack_trunc(float hi, float lo) {
#if __has_builtin(__builtin_amdgcn_perm)
    return __builtin_amdgcn_perm(__builtin_bit_cast(unsigned, hi),
                                 __builtin_bit_cast(unsigned, lo), 0x07060302u);
#else
    return (__builtin_bit_cast(unsigned, hi) & 0xffff0000u) |
           (__builtin_bit_cast(unsigned, lo) >> 16);
#endif
}

// async global->LDS, 16B/lane; lds dest = wave-uniform base + lane*16
static __device__ __forceinline__ void load_lds16(const void* g, void* l) {
    __builtin_amdgcn_global_load_lds(
        (__attribute__((address_space(1))) void*)(g),
        (__attribute__((address_space(3))) void*)(l), 16, 0, 0);
}

// ---------------------------------------------------------------------------
// Kernel X: X (f32 or bf16) -> Xb bf16 [4096,1024] (Xb lives in d_out).
// Per-block dtype detection (64 samples of the block's own region); block 0
// publishes the flag for downstream kernels (stream-ordered).
// ---------------------------------------------------------------------------
__global__ __launch_bounds__(256) void k_cvt_x(const void* __restrict__ Xv,
                                               ushort_t* __restrict__ Xb,
                                               int* __restrict__ flagp) {
    __shared__ int cnt;
    if (threadIdx.x == 0) cnt = 0;
    __syncthreads();
    const unsigned* X32 = (const unsigned*)Xv;
    if (threadIdx.x < 64) {
        // words [b*2048,(b+1)*2048) are in-bounds for both dtype interpretations
        unsigned u = X32[(size_t)blockIdx.x * 2048 + threadIdx.x * 32 + 7];
        int bexp = (u >> 7) & 0xFF;
        if (bexp >= 0x68 && bexp <= 0x90) atomicAdd(&cnt, 1);
    }
    __syncthreads();
    const int isf32 = (cnt < 32);               // bf16 -> ~64 hits; f32 -> ~10
    if (blockIdx.x == 0 && threadIdx.x == 0) *flagp = isf32;

    const size_t base = ((size_t)blockIdx.x * 256 + threadIdx.x) * 16;
    if (isf32) {
        const float* Xf = (const float*)Xv;
        ushort_t tmp[16];
#pragma unroll
        for (int c = 0; c < 4; ++c) {
            float4 v = *(const float4*)(Xf + base + c * 4);
            tmp[c * 4 + 0] = f2bf(v.x); tmp[c * 4 + 1] = f2bf(v.y);
            tmp[c * 4 + 2] = f2bf(v.z); tmp[c * 4 + 3] = f2bf(v.w);
        }
        *(float4*)(Xb + base)     = ((const float4*)tmp)[0];
        *(float4*)(Xb + base + 8) = ((const float4*)tmp)[1];
    } else {
        const ushort_t* Xh = (const ushort_t*)Xv;
        *(float4*)(Xb + base)     = *(const float4*)(Xh + base);
        *(float4*)(Xb + base + 8) = *(const float4*)(Xh + base + 8);
    }
}

// ---------------------------------------------------------------------------
// Kernel A: W_qkv [h][D][e] (f32 or bf16) -> Wt [h*192+e][D] bf16 (3072 x 1024)
// ---------------------------------------------------------------------------
__global__ __launch_bounds__(256) void k_cvt_w(const void* __restrict__ Wv,
                                               ushort_t* __restrict__ Wt,
                                               const int* __restrict__ flagp) {
    __shared__ ushort_t tile[64][72];
    const int isf32 = *flagp;
    const int h  = blockIdx.x;
    const int dt = blockIdx.y;
    const int et = blockIdx.z;
    const int D0 = dt * 64, e0 = et * 64;
    const int t  = threadIdx.x;
#pragma unroll
    for (int r = 0; r < 2; ++r) {
        int row = r * 32 + (t >> 3);
        int col = (t & 7) * 8;
        size_t base = ((size_t)(h * HID + D0 + row)) * E3 + e0 + col;
        if (isf32) {
            const float* Wf = (const float*)Wv;
            float4 a = *(const float4*)(Wf + base);
            float4 c = *(const float4*)(Wf + base + 4);
            tile[row][col + 0] = f2bf(a.x); tile[row][col + 1] = f2bf(a.y);
            tile[row][col + 2] = f2bf(a.z); tile[row][col + 3] = f2bf(a.w);
            tile[row][col + 4] = f2bf(c.x); tile[row][col + 5] = f2bf(c.y);
            tile[row][col + 6] = f2bf(c.z); tile[row][col + 7] = f2bf(c.w);
        } else {
            *(float4*)&tile[row][col] = *(const float4*)((const ushort_t*)Wv + base);
        }
    }
    __syncthreads();
#pragma unroll
    for (int r = 0; r < 2; ++r) {
        int erow = r * 32 + (t >> 3);
        int dcol = (t & 7) * 8;
        ushort_t vals[8];
#pragma unroll
        for (int i = 0; i < 8; ++i) vals[i] = tile[dcol + i][erow];
        *(float4*)(Wt + ((size_t)(h * E3 + e0 + erow)) * HID + D0 + dcol) = *(float4*)vals;
    }
}

// ---------------------------------------------------------------------------
// Kernel B: fused QKV GEMM, m97-style: global_load_lds dwordx4 into unpadded
// XOR-swizzled LDS (colblock' = colblock ^ (row&7)), BK=64, 2 barriers/iter.
// ---------------------------------------------------------------------------
__global__ __launch_bounds__(256) void k_qkv(const ushort_t* __restrict__ Xb,
                                             const ushort_t* __restrict__ Wt,
                                             ushort_t* __restrict__ Qb,
                                             ushort_t* __restrict__ Kb,
                                             ushort_t* __restrict__ Vtb) {
    __shared__ __align__(16) ushort_t smem[2 * 128 * 64];   // Xl | Wl; Vbuf overlays
    ushort_t* Xl = smem;
    ushort_t* Wl = smem + 128 * 64;

    const int e0 = blockIdx.x * 128;            // col tile (24)
    const int m0 = blockIdx.y * 128;            // row tile (32)
    const int b  = m0 >> 11;
    const int n0 = m0 & 2047;
    const int t = threadIdx.x;
    const int w = t >> 6, lane = t & 63, l15 = lane & 15, quad = lane >> 4;
    const int wrow0 = (w & 1) * 64, wcol0 = (w >> 1) * 64;
    const int srow = lane >> 3;                 // 0..7
    const int scb  = (lane & 7) ^ srow;         // swizzled global colblock

    f32x4 acc[4][4];
#pragma unroll
    for (int i = 0; i < 4; ++i)
#pragma unroll
        for (int j = 0; j < 4; ++j) acc[i][j] = (f32x4){0.f, 0.f, 0.f, 0.f};

    for (int k0 = 0; k0 < HID; k0 += 64) {
        __syncthreads();                        // prev frag reads done
#pragma unroll
        for (int cc = 0; cc < 4; ++cc) {
            const int ch  = w * 4 + cc;         // chunk 0..15 (wave-uniform)
            const int row = ch * 8 + srow;      // 0..127
            load_lds16(Xb + (size_t)(m0 + row) * HID + k0 + scb * 8, &Xl[ch * 512]);
            load_lds16(Wt + (size_t)(e0 + row) * HID + k0 + scb * 8, &Wl[ch * 512]);
        }
        __syncthreads();                        // drains vmcnt -> tiles ready
#pragma unroll
        for (int kh = 0; kh < 2; ++kh) {
            short8 af[4], bfm[4];
#pragma unroll
            for (int i = 0; i < 4; ++i) {
                const int r = wrow0 + i * 16 + l15;
                af[i] = *(const short8*)&Xl[r * 64 + ((kh * 4 + quad) ^ (r & 7)) * 8];
            }
#pragma unroll
            for (int j = 0; j < 4; ++j) {
                const int r = wcol0 + j * 16 + l15;
                bfm[j] = *(const short8*)&Wl[r * 64 + ((kh * 4 + quad) ^ (r & 7)) * 8];
            }
#pragma unroll
            for (int i = 0; i < 4; ++i)
#pragma unroll
                for (int j = 0; j < 4; ++j)
                    acc[i][j] = MFMA16(af[i], bfm[j], acc[i][j]);
        }
    }

    // ---- epilogue ----
    ushort_t* Vbuf = smem;                      // 64 x 136
    __syncthreads();
#pragma unroll
    for (int i = 0; i < 4; ++i) {
#pragma unroll
        for (int j = 0; j < 4; ++j) {
            const int E0v = e0 + wcol0 + j * 16;        // uniform; 16 | 192 so one head
            const int hh  = E0v / 192;
            const int r0  = E0v - hh * 192;
            const int bh  = b * NH + hh;
            const int nb  = n0 + wrow0 + i * 16 + quad * 4;
            if (r0 < 64) {                      // Q (pre-scaled by QSCALE)
                const int e = r0 + l15;
#pragma unroll
                for (int reg = 0; reg < 4; ++reg)
                    Qb[((size_t)bh * SEQ + nb + reg) * HD + e] = f2bf(acc[i][j][reg] * QSCALE);
            } else if (r0 < 128) {              // K
                const int e = r0 - 64 + l15;
#pragma unroll
                for (int reg = 0; reg < 4; ++reg)
                    Kb[((size_t)bh * SEQ + nb + reg) * HD + e] = f2bf(acc[i][j][reg]);
            } else {                            // V -> LDS transpose buffer
                const int d  = r0 - 128 + l15;
                const int nl = wrow0 + i * 16 + quad * 4;
#pragma unroll
                for (int reg = 0; reg < 4; ++reg)
                    Vbuf[d * 136 + nl + reg] = f2bf(acc[i][j][reg]);
            }
        }
    }
    const int m3 = blockIdx.x % 3;
    if (m3 != 0) {
        __syncthreads();
        const int hv  = (e0 + ((m3 == 1) ? 0 : 64)) / 192;
        const int bhv = b * NH + hv;
        const int dr = t >> 2, part = t & 3;
        size_t dst = ((size_t)bhv * HD + dr) * SEQ + n0 + part * 32;
#pragma unroll
        for (int c = 0; c < 4; ++c) {
            float4 v = *(const float4*)&Vbuf[dr * 136 + part * 32 + c * 8];
            *(float4*)(Vtb + dst + c * 8) = v;
        }
    }
}

// ---------------------------------------------------------------------------
// Kernel C: flash attention, S^T = K*Q^T. 512 threads, 128 q-rows/block.
// TRIPLE-buffered async K/V staging, raw s_barrier + manual vmcnt:
//   top of iter j: s_waitcnt vmcnt(2) retires pair(j) (pair(j+1) stays in
//   flight); raw s_barrier => every wave's pair(j) retired => buf ready;
//   then issue pair(j+2). Each prefetch gets 2 compute phases to land.
// PV consumes P directly from registers via K=16 MFMAs (layout identity:
// S^T C-layout == 16x16x16 B-layout). V read as 16x ds_read_b64.
// ---------------------------------------------------------------------------
__global__ __launch_bounds__(512) void k_attn(const ushort_t* __restrict__ Qb,
                                              const ushort_t* __restrict__ Kb,
                                              const ushort_t* __restrict__ Vtb,
                                              const int* __restrict__ mask,
                                              void* __restrict__ outv,
                                              const int* __restrict__ flagp) {
    __shared__ __align__(16) char smem_raw[57344];
    // bufs: 3 x 16384 B (K 8192 | V 8192); bias at 49152 (8192 B)
    float* biasl = (float*)(smem_raw + 49152);

    const int isf32 = *flagp;
    const int q0 = blockIdx.x * 128;
    const int bh = blockIdx.y;
    const int b  = bh >> 4, h = bh & 15;
    const int t  = threadIdx.x;
    const int w  = t >> 6, lane = t & 63, l15 = lane & 15, quad = lane >> 4;
    const int srow = lane >> 3;
    const int scb  = (lane & 7) ^ srow;
    const int row8 = w * 8 + srow;              // this wave's staging row (0..63)

    const f32x4 zero4 = {0.f, 0.f, 0.f, 0.f};

    // issue pair(0)->buf0, pair(1)->buf1 (drained by the setup barrier: ready)
#pragma unroll
    for (int tj = 0; tj < 2; ++tj) {
        ushort_t* kb = (ushort_t*)(smem_raw + tj * 16384);
        ushort_t* vb = kb + 4096;
        load_lds16(Kb  + ((size_t)bh * SEQ + tj * 64 + row8) * HD + scb * 8, &kb[w * 512]);
        load_lds16(Vtb + ((size_t)bh * HD + row8) * SEQ + tj * 64 + scb * 8, &vb[w * 512]);
    }

    int lm = 0;
    for (int i = t; i < SEQ; i += 512) {
        int mv = mask[b * SEQ + i];
        biasl[i] = mv ? 0.0f : MBIAS;
        lm |= (mv == 0);
    }
    // Q fragments (loaded before the setup barrier; barrier drains them too)
    const int qrow = q0 + w * 16 + l15;
    short8 qa0 = *(const short8*)(Qb + ((size_t)bh * SEQ + qrow) * HD + quad * 8);
    short8 qa1 = *(const short8*)(Qb + ((size_t)bh * SEQ + qrow) * HD + 32 + quad * 8);

    const int use_bias = __syncthreads_or(lm);  // full drain: vmcnt -> 0 here

    f32x4 o[4];
#pragma unroll
    for (int mt = 0; mt < 4; ++mt) o[mt] = zero4;
    float l_r = 0.f;

    for (int j0 = 0; j0 < SEQ; j0 += 64) {
        const int idx = (j0 >> 6) % 3;
        // retire this tile's pair; keep next tile's pair in flight
        if (j0 + 64 < SEQ) { asm volatile("s_waitcnt vmcnt(2)" ::: "memory"); }
        else               { asm volatile("s_waitcnt vmcnt(0)" ::: "memory"); }
        __builtin_amdgcn_s_barrier();           // raw: no compiler vmcnt(0) drain
        asm volatile("" ::: "memory");
        if (j0 + 128 < SEQ) {                   // stage tile j+2 into buf[(idx+2)%3]
            ushort_t* kb = (ushort_t*)(smem_raw + ((idx + 2) % 3) * 16384);
            ushort_t* vb = kb + 4096;
            load_lds16(Kb  + ((size_t)bh * SEQ + j0 + 128 + row8) * HD + scb * 8, &kb[w * 512]);
            load_lds16(Vtb + ((size_t)bh * HD + row8) * SEQ + j0 + 128 + scb * 8, &vb[w * 512]);
        }
        ushort_t* kb = (ushort_t*)(smem_raw + idx * 16384);
        ushort_t* vb = kb + 4096;

        // ---- S^T tiles: A = K rows, B = Q rows ----
        f32x4 s[4];
#pragma unroll
        for (int jt = 0; jt < 4; ++jt) {
            const int rk = jt * 16 + l15;
            short8 kb0 = *(const short8*)&kb[rk * 64 + ((quad)     ^ (rk & 7)) * 8];
            short8 kb1 = *(const short8*)&kb[rk * 64 + ((4 + quad) ^ (rk & 7)) * 8];
            s[jt] = MFMA16(kb0, qa0, zero4);
            s[jt] = MFMA16(kb1, qa1, s[jt]);
        }
        if (use_bias) {
#pragma unroll
            for (int jt = 0; jt < 4; ++jt) {
                float4 bj = *(const float4*)&biasl[j0 + jt * 16 + quad * 4];
#pragma unroll
                for (int reg = 0; reg < 4; ++reg)
                    s[jt][reg] += ((const float*)&bj)[reg];
            }
        }

        // ---- p = 2^s; pack; P stays in registers (B-frag of 16x16x16) ----
        short4v pb[4];
#pragma unroll
        for (int jt = 0; jt < 4; ++jt) {
            float p0 = EXP2(s[jt][0]);
            float p1 = EXP2(s[jt][1]);
            float p2 = EXP2(s[jt][2]);
            float p3 = EXP2(s[jt][3]);
            l_r += (p0 + p1) + (p2 + p3);
            uint2 u;
            u.x = pack_trunc(p1, p0);
            u.y = pack_trunc(p3, p2);
            pb[jt] = __builtin_bit_cast(short4v, u);
        }

        // ---- PV: o[d][q] += V^T[d][k] * P[k][q], K=16 per MFMA ----
        // A-frag (V^T): lane(l15,quad) needs n = 16*jt + 4*quad + e, i.e.
        // logical colblock 2*jt + (quad>>1), ushort offset 4*(quad&1).
#pragma unroll
        for (int mt = 0; mt < 4; ++mt) {
            const int rv = mt * 16 + l15;
            const int rx = rv & 7;
#pragma unroll
            for (int jt = 0; jt < 4; ++jt) {
                short4v va = *(const short4v*)&vb[rv * 64 +
                    (((2 * jt + (quad >> 1)) ^ rx) * 8 + 4 * (quad & 1))];
                o[mt] = MFMA16K16(va, pb[jt], o[mt]);
            }
        }
    }

    // ---- l reduce + coalesced store ----
    l_r += __shfl_xor(l_r, 16);
    l_r += __shfl_xor(l_r, 32);
    const float rinv = 1.0f / l_r;

    __syncthreads();
    const int r = t >> 2, part = t & 3;         // r covers 0..127
    if (!isf32) {
        ushort_t* Ol = (ushort_t*)smem_raw;     // [q_local][d] stride 72, 128 rows
#pragma unroll
        for (int mt = 0; mt < 4; ++mt) {
            uint2 u;
            u.x = (unsigned)f2bf(o[mt][0] * rinv) | ((unsigned)f2bf(o[mt][1] * rinv) << 16);
            u.y = (unsigned)f2bf(o[mt][2] * rinv) | ((unsigned)f2bf(o[mt][3] * rinv) << 16);
            *(uint2*)&Ol[(w * 16 + l15) * 72 + mt * 16 + quad * 4] = u;
        }
        __syncthreads();
        float4 v0 = *(const float4*)&Ol[r * 72 + part * 16];
        float4 v1 = *(const float4*)&Ol[r * 72 + part * 16 + 8];
        ushort_t* outp = (ushort_t*)outv;
        size_t dst = ((size_t)b * SEQ + q0 + r) * HID + h * HD + part * 16;
        *(float4*)(outp + dst)     = v0;
        *(float4*)(outp + dst + 8) = v1;
    } else {
        float* Olf = (float*)smem_raw;          // [q_local][d] stride 68, 128 rows
#pragma unroll
        for (int mt = 0; mt < 4; ++mt)
#pragma unroll
            for (int reg = 0; reg < 4; ++reg)
                Olf[(w * 16 + l15) * 68 + mt * 16 + quad * 4 + reg] = o[mt][reg] * rinv;
        __syncthreads();
        float* outp = (float*)outv;
        size_t dst = ((size_t)b * SEQ + q0 + r) * HID + h * HD + part * 16;
#pragma unroll
        for (int c = 0; c < 4; ++c) {
            float4 v = *(const float4*)&Olf[r * 68 + part * 16 + c * 4];
            *(float4*)(outp + dst + c * 4) = v;
        }
    }
}

// ---------------------------------------------------------------------------
extern "C" void kernel_launch(void* const* d_in, const int* in_sizes, int n_in,
                              void* d_out, int out_size, void* d_ws, size_t ws_size,
                              hipStream_t stream) {
    const void* X    = d_in[0];                 // hidden_states [2,2048,1024] f32 or bf16
    const int*  mask = (const int*)d_in[1];     // attention_mask i32 [2,2048]
    const void* W    = d_in[2];                 // W_qkv [16,1024,192] f32 or bf16

    char* ws = (char*)d_ws;
    // ws: Q 8MB | K 8MB | Vt 8MB | Wt 6MB | flag.  Xb (bf16 X) lives in d_out.
    ushort_t* Qb    = (ushort_t*)(ws);
    ushort_t* Kb    = (ushort_t*)(ws + 8388608);
    ushort_t* Vtb   = (ushort_t*)(ws + 16777216);
    ushort_t* Wtb   = (ushort_t*)(ws + 25165824);
    int*      flagp = (int*)(ws + 31457280);
    ushort_t* Xb    = (ushort_t*)d_out;

    k_cvt_x<<<1024, 256, 0, stream>>>(X, Xb, flagp);
    k_cvt_w<<<dim3(16, 16, 3), 256, 0, stream>>>(W, Wtb, flagp);
    k_qkv<<<dim3(24, 32), 256, 0, stream>>>(Xb, Wtb, Qb, Kb, Vtb);
    k_attn<<<dim3(16, 32), 512, 0, stream>>>(Qb, Kb, Vtb, mask, d_out, flagp);
}